// Round 1
// baseline (553.523 us; speedup 1.0000x reference)
//
#include <hip/hip_runtime.h>
#include <math.h>

// LSTM: B=1024, T=512, IN=16, H=64, OUT=8, gate order i,f,g,o.
// One block (256 threads) per batch element; thread g owns gate row g with
// W_ih row (16) + W_hh row (64) in registers. h broadcast via LDS float4
// reads (wave-uniform addr => HW broadcast). c state in regs of threads 0..63.
// __launch_bounds__(256,4): 4 waves/EU => 4 blocks/CU (1024 blocks / 256 CUs),
// VGPR cap 128.

#define LSTM_B 1024
#define LSTM_T 512
#define LSTM_IN 16
#define LSTM_H 64
#define LSTM_G 256   // 4*H
#define LSTM_OUT 8

__device__ __forceinline__ float fast_sigmoid(float x) {
    // exp(-x) -> inf for very negative x gives 1/(1+inf)=0, no NaN; no clamp needed.
    return 1.0f / (1.0f + __expf(-x));
}

__device__ __forceinline__ float fast_tanh(float x) {
    // tanh(x) = (1 - e^{-2x}) / (1 + e^{-2x}); clamp exp arg to avoid inf/inf NaN.
    float a = fminf(fmaxf(-2.0f * x, -80.0f), 80.0f);
    float e = __expf(a);
    return (1.0f - e) / (1.0f + e);
}

__global__ __launch_bounds__(256, 4)
void lstm_fused_kernel(const float* __restrict__ x,
                       const float* __restrict__ W_ih,
                       const float* __restrict__ W_hh,
                       const float* __restrict__ b_ih,
                       const float* __restrict__ b_hh,
                       const float* __restrict__ W_fc,
                       const float* __restrict__ b_fc,
                       float* __restrict__ out) {
    const int b    = blockIdx.x;       // batch element
    const int g    = threadIdx.x;      // gate row 0..255
    const int wave = g >> 6;           // 0:i 1:f 2:g 3:o (wave-uniform activation)

    __shared__ float hsh[LSTM_H];      // h state (broadcast source)
    __shared__ float xsh[LSTM_IN];     // current x_t
    __shared__ float act[LSTM_G];      // activated gates

    // ---- load this thread's weight rows into registers ----
    float wih[LSTM_IN];
    float whh[LSTM_H];
    {
        const float4* wi4 = reinterpret_cast<const float4*>(W_ih + g * LSTM_IN);
        #pragma unroll
        for (int k = 0; k < LSTM_IN / 4; ++k) {
            float4 v = wi4[k];
            wih[4*k+0] = v.x; wih[4*k+1] = v.y; wih[4*k+2] = v.z; wih[4*k+3] = v.w;
        }
        const float4* wh4 = reinterpret_cast<const float4*>(W_hh + g * LSTM_H);
        #pragma unroll
        for (int k = 0; k < LSTM_H / 4; ++k) {
            float4 v = wh4[k];
            whh[4*k+0] = v.x; whh[4*k+1] = v.y; whh[4*k+2] = v.z; whh[4*k+3] = v.w;
        }
    }
    const float bias = b_ih[g] + b_hh[g];

    float c = 0.0f;                    // c[g] held by threads g<64
    if (g < LSTM_H) hsh[g] = 0.0f;

    // x prefetch: threads 0..3 hold the next step's 16 floats as float4
    const float4* xg4 = reinterpret_cast<const float4*>(x + (size_t)b * LSTM_T * LSTM_IN);
    float4 xreg = make_float4(0.f, 0.f, 0.f, 0.f);
    if (g < 4) xreg = xg4[g];

    for (int t = 0; t < LSTM_T; ++t) {
        if (g < 4) reinterpret_cast<float4*>(xsh)[g] = xreg;
        __syncthreads();   // x_t and h_{t-1} visible to all

        // prefetch next x_t while we compute (hides global-load latency)
        if (g < 4 && t + 1 < LSTM_T) xreg = xg4[(t + 1) * 4 + g];

        // gate pre-activation: bias + x_t . W_ih[g] + h . W_hh[g]
        float a0 = bias, a1 = 0.f, a2 = 0.f, a3 = 0.f;  // 4 accs break dep chain
        const float4* x4 = reinterpret_cast<const float4*>(xsh);
        #pragma unroll
        for (int k = 0; k < LSTM_IN / 4; ++k) {
            float4 v = x4[k];
            a0 = fmaf(wih[4*k+0], v.x, a0);
            a1 = fmaf(wih[4*k+1], v.y, a1);
            a2 = fmaf(wih[4*k+2], v.z, a2);
            a3 = fmaf(wih[4*k+3], v.w, a3);
        }
        const float4* h4 = reinterpret_cast<const float4*>(hsh);
        #pragma unroll
        for (int k = 0; k < LSTM_H / 4; ++k) {
            float4 v = h4[k];
            a0 = fmaf(whh[4*k+0], v.x, a0);
            a1 = fmaf(whh[4*k+1], v.y, a1);
            a2 = fmaf(whh[4*k+2], v.z, a2);
            a3 = fmaf(whh[4*k+3], v.w, a3);
        }
        float acc = (a0 + a1) + (a2 + a3);

        // activation (wave-uniform branch: wave 2 = g-gate -> tanh)
        float a = (wave == 2) ? fast_tanh(acc) : fast_sigmoid(acc);
        act[g] = a;
        __syncthreads();   // all gates visible

        // state update by threads 0..63 (write is covered by next iter's sync)
        if (g < LSTM_H) {
            float gi = act[g];
            float gf = act[LSTM_H + g];
            float gg = act[2 * LSTM_H + g];
            float go = act[3 * LSTM_H + g];
            c = fmaf(gf, c, gi * gg);
            hsh[g] = go * fast_tanh(c);
        }
    }
    __syncthreads();

    // epilogue: out[b][o] = sigmoid(h . W_fc[o] + b_fc[o]), o = 0..7 (once per block)
    if (g < LSTM_OUT) {
        const float* wf = W_fc + g * LSTM_H;
        float acc = b_fc[g];
        #pragma unroll 8
        for (int j = 0; j < LSTM_H; ++j) acc = fmaf(wf[j], hsh[j], acc);
        out[(size_t)b * LSTM_OUT + g] = fast_sigmoid(acc);
    }
}

extern "C" void kernel_launch(void* const* d_in, const int* in_sizes, int n_in,
                              void* d_out, int out_size, void* d_ws, size_t ws_size,
                              hipStream_t stream) {
    const float* x    = (const float*)d_in[0];
    const float* W_ih = (const float*)d_in[1];
    const float* W_hh = (const float*)d_in[2];
    const float* b_ih = (const float*)d_in[3];
    const float* b_hh = (const float*)d_in[4];
    const float* W_fc = (const float*)d_in[5];
    const float* b_fc = (const float*)d_in[6];
    float* out = (float*)d_out;

    lstm_fused_kernel<<<LSTM_B, LSTM_G, 0, stream>>>(
        x, W_ih, W_hh, b_ih, b_hh, W_fc, b_fc, out);
}

// Round 2
// 525.441 us; speedup vs baseline: 1.0534x; 1.0534x over previous
//
#include <hip/hip_runtime.h>
#include <math.h>

// LSTM: B=1024, T=512, IN=16, H=64, OUT=8, gate order i,f,g,o. fp32.
// One block (256 threads) per batch element; thread g owns gate row g.
// Weights held in 20 NAMED float4 registers (defeats compiler remat that
// produced VGPR=56 in R1). h broadcast via wave-uniform LDS float4 reads.
// State update done redundantly by all 4 waves (identical inputs -> benign
// same-value race) so no wave sits idle. Activations use v_rcp_f32 instead
// of full-precision division.

#define LSTM_B 1024
#define LSTM_T 512
#define LSTM_IN 16
#define LSTM_H 64
#define LSTM_G 256   // 4*H
#define LSTM_OUT 8

__device__ __forceinline__ float fast_rcp(float x) {
    return __builtin_amdgcn_rcpf(x);   // v_rcp_f32, ~1 ulp
}

__device__ __forceinline__ float fast_sigmoid(float x) {
    // 1/(1+e^{-x}); e^{-x}->inf for very negative x gives rcp(inf)=0. No NaN.
    return fast_rcp(1.0f + __expf(-x));
}

__device__ __forceinline__ float fast_tanh(float x) {
    // (1 - e^{-2x}) * rcp(1 + e^{-2x}); clamp exp arg above to avoid inf-inf.
    float a = fminf(-2.0f * x, 80.0f);
    float e = __expf(a);
    return (1.0f - e) * fast_rcp(1.0f + e);
}

__global__ __launch_bounds__(256, 4)
void lstm_fused_kernel(const float* __restrict__ x,
                       const float* __restrict__ W_ih,
                       const float* __restrict__ W_hh,
                       const float* __restrict__ b_ih,
                       const float* __restrict__ b_hh,
                       const float* __restrict__ W_fc,
                       const float* __restrict__ b_fc,
                       float* __restrict__ out) {
    const int b    = blockIdx.x;       // batch element
    const int g    = threadIdx.x;      // gate row 0..255
    const int wave = g >> 6;           // 0:i 1:f 2:g 3:o (wave-uniform activation)
    const int j    = g & 63;           // hidden index this thread updates

    __shared__ float hsh[LSTM_H];      // h state (broadcast source)
    __shared__ float xsh[LSTM_IN];     // current x_t
    __shared__ float act[LSTM_G];      // activated gates

    // ---- weight rows in NAMED float4 registers ----
    const float4* wi4 = reinterpret_cast<const float4*>(W_ih + g * LSTM_IN);
    float4 wih0 = wi4[0], wih1 = wi4[1], wih2 = wi4[2], wih3 = wi4[3];

    const float4* wh4 = reinterpret_cast<const float4*>(W_hh + g * LSTM_H);
    float4 whh0  = wh4[0],  whh1  = wh4[1],  whh2  = wh4[2],  whh3  = wh4[3];
    float4 whh4  = wh4[4],  whh5  = wh4[5],  whh6  = wh4[6],  whh7  = wh4[7];
    float4 whh8  = wh4[8],  whh9  = wh4[9],  whh10 = wh4[10], whh11 = wh4[11];
    float4 whh12 = wh4[12], whh13 = wh4[13], whh14 = wh4[14], whh15 = wh4[15];

    const float bias = b_ih[g] + b_hh[g];

    float c = 0.0f;                    // c[j], kept consistently in all 4 waves
    if (g < LSTM_H) hsh[g] = 0.0f;

    // x prefetch: threads 0..3 hold next step's 16 floats as one float4 each
    const float4* xg4 = reinterpret_cast<const float4*>(x + (size_t)b * LSTM_T * LSTM_IN);
    float4 xreg = make_float4(0.f, 0.f, 0.f, 0.f);
    if (g < 4) xreg = xg4[g];

    for (int t = 0; t < LSTM_T; ++t) {
        if (g < 4) reinterpret_cast<float4*>(xsh)[g] = xreg;
        __syncthreads();   // x_t and h_{t-1} visible to all

        // prefetch next x_t while we compute (hides global-load latency)
        if (g < 4 && t + 1 < LSTM_T) xreg = xg4[(t + 1) * 4 + g];

        // gate pre-activation: bias + x_t . W_ih[g] + h . W_hh[g]
        float a0 = bias, a1 = 0.f, a2 = 0.f, a3 = 0.f;  // 4 accs break dep chain
        const float4* x4 = reinterpret_cast<const float4*>(xsh);
        const float4* h4 = reinterpret_cast<const float4*>(hsh);

#define FMA4(W, V) \
        { float4 v_ = (V); \
          a0 = fmaf((W).x, v_.x, a0); \
          a1 = fmaf((W).y, v_.y, a1); \
          a2 = fmaf((W).z, v_.z, a2); \
          a3 = fmaf((W).w, v_.w, a3); }

        FMA4(wih0, x4[0]); FMA4(wih1, x4[1]); FMA4(wih2, x4[2]); FMA4(wih3, x4[3]);
        FMA4(whh0,  h4[0]);  FMA4(whh1,  h4[1]);  FMA4(whh2,  h4[2]);  FMA4(whh3,  h4[3]);
        FMA4(whh4,  h4[4]);  FMA4(whh5,  h4[5]);  FMA4(whh6,  h4[6]);  FMA4(whh7,  h4[7]);
        FMA4(whh8,  h4[8]);  FMA4(whh9,  h4[9]);  FMA4(whh10, h4[10]); FMA4(whh11, h4[11]);
        FMA4(whh12, h4[12]); FMA4(whh13, h4[13]); FMA4(whh14, h4[14]); FMA4(whh15, h4[15]);
#undef FMA4

        float acc = (a0 + a1) + (a2 + a3);

        // activation (wave-uniform branch: wave 2 = g-gate -> tanh)
        act[g] = (wave == 2) ? fast_tanh(acc) : fast_sigmoid(acc);
        __syncthreads();   // all gates visible

        // state update — done redundantly by ALL waves (identical inputs ->
        // identical results; same-value race on hsh is benign). No idle waves.
        float gi = act[j];
        float gf = act[LSTM_H + j];
        float gg = act[2 * LSTM_H + j];
        float go = act[3 * LSTM_H + j];
        c = fmaf(gf, c, gi * gg);
        hsh[j] = go * fast_tanh(c);    // write covered by next iter's sync
    }
    __syncthreads();

    // epilogue: out[b][o] = sigmoid(h . W_fc[o] + b_fc[o]), o = 0..7
    if (g < LSTM_OUT) {
        const float* wf = W_fc + g * LSTM_H;
        float acc = b_fc[g];
        #pragma unroll 8
        for (int k = 0; k < LSTM_H; ++k) acc = fmaf(wf[k], hsh[k], acc);
        out[(size_t)b * LSTM_OUT + g] = fast_sigmoid(acc);
    }
}

extern "C" void kernel_launch(void* const* d_in, const int* in_sizes, int n_in,
                              void* d_out, int out_size, void* d_ws, size_t ws_size,
                              hipStream_t stream) {
    const float* x    = (const float*)d_in[0];
    const float* W_ih = (const float*)d_in[1];
    const float* W_hh = (const float*)d_in[2];
    const float* b_ih = (const float*)d_in[3];
    const float* b_hh = (const float*)d_in[4];
    const float* W_fc = (const float*)d_in[5];
    const float* b_fc = (const float*)d_in[6];
    float* out = (float*)d_out;

    lstm_fused_kernel<<<LSTM_B, LSTM_G, 0, stream>>>(
        x, W_ih, W_hh, b_ih, b_hh, W_fc, b_fc, out);
}

// Round 3
// 401.075 us; speedup vs baseline: 1.3801x; 1.3101x over previous
//
#include <hip/hip_runtime.h>
#include <math.h>

// LSTM B=1024,T=512,IN=16,H=64,OUT=8, gates i,f,g,o. MFMA restructure:
// G[256 x 2] = [W_ih|W_hh|0][256x96] . [x;h;0][96x2] per step via
// mfma_f32_16x16x32_bf16. 512 blocks x 256 thr (Btile=2 batches/block,
// 2 blocks/CU). Weights as split-bf16 (hi+lo) A-fragments pinned in VGPRs
// with opaque asm (R1/R2 showed the compiler remats invariant global loads
// otherwise: VGPR stuck at 56-60, L1-bound at ~530us). B-frag cols
// replicated via lane&1 -> only batches 0,1 real, cols conflict-free
// broadcasts. fp32 C-accum + bias preloaded into acc init.

#define LSTM_T 512
#define LSTM_IN 16
#define LSTM_H 64
#define LSTM_G 256
#define LSTM_OUT 8
#define BT 2               // batches per block
#define XH 96              // xh row stride in shorts: 16 x | 64 h | 16 zero pad

typedef short  short8  __attribute__((ext_vector_type(8)));
typedef float  floatx4 __attribute__((ext_vector_type(4)));

static __device__ __forceinline__ unsigned f2bf(float f) {
    unsigned u = __float_as_uint(f);
    return (u + 0x7FFFu + ((u >> 16) & 1u)) >> 16;   // RNE f32 -> bf16
}
static __device__ __forceinline__ float bf2f(unsigned s) {
    return __uint_as_float(s << 16);
}
static __device__ __forceinline__ float fast_rcp(float x) { return __builtin_amdgcn_rcpf(x); }
static __device__ __forceinline__ float sigm(float x) { return fast_rcp(1.0f + __expf(-x)); }
static __device__ __forceinline__ float tanh_(float x) {
    float a = fminf(-2.0f * x, 80.0f);
    float e = __expf(a);
    return (1.0f - e) * fast_rcp(1.0f + e);
}
static __device__ __forceinline__ void pin4(int4& v) {
    asm volatile("" : "+v"(v.x), "+v"(v.y), "+v"(v.z), "+v"(v.w));
}
static __device__ __forceinline__ void pinf4(float4& v) {
    asm volatile("" : "+v"(v.x), "+v"(v.y), "+v"(v.z), "+v"(v.w));
}

// 8 floats -> split bf16 hi/lo packed as int4 each (element j = short j)
static __device__ __forceinline__ void cvt8(float4 a, float4 b, int4& hi, int4& lo) {
    float f[8] = {a.x, a.y, a.z, a.w, b.x, b.y, b.z, b.w};
    unsigned h[8], l[8];
    #pragma unroll
    for (int j = 0; j < 8; ++j) {
        h[j] = f2bf(f[j]);
        l[j] = f2bf(f[j] - bf2f(h[j]));
    }
    hi = make_int4((int)(h[0] | (h[1] << 16)), (int)(h[2] | (h[3] << 16)),
                   (int)(h[4] | (h[5] << 16)), (int)(h[6] | (h[7] << 16)));
    lo = make_int4((int)(l[0] | (l[1] << 16)), (int)(l[2] | (l[3] << 16)),
                   (int)(l[4] | (l[5] << 16)), (int)(l[6] | (l[7] << 16)));
}

__global__ __launch_bounds__(256, 2)
void lstm_mfma_kernel(const float* __restrict__ x,
                      const float* __restrict__ W_ih,
                      const float* __restrict__ W_hh,
                      const float* __restrict__ b_ih,
                      const float* __restrict__ b_hh,
                      const float* __restrict__ W_fc,
                      const float* __restrict__ b_fc,
                      float* __restrict__ out) {
    const int tid   = threadIdx.x;
    const int lane  = tid & 63;
    const int wave  = tid >> 6;
    const int q     = lane >> 4;      // quad 0..3 -> k = 8q..8q+7
    const int m     = lane & 15;      // A row (gate-in-tile) / C col
    const int nb    = lane & 1;       // replicated B column -> batch 0/1
    const int bbase = blockIdx.x * BT;

    __shared__ __align__(16) short xh[BT][XH];         // bf16: x|h|pad per batch
    __shared__ __align__(16) float pre[BT][LSTM_G];    // preacts / final h

    // ---- preload weights as pinned split-bf16 A-fragments ----
    // K layout: k0-15 = W_ih row, k16-79 = W_hh row, k80-95 = 0.
    int4 Ahi[4][3], Alo[4][3];
    float4 bias4[4];
    #pragma unroll
    for (int tt = 0; tt < 4; ++tt) {
        const int gt = wave * 64 + tt * 16 + m;        // gate row for A-frag
        #pragma unroll
        for (int c = 0; c < 3; ++c) {
            const float* src = nullptr;
            if (c == 0)      src = (q < 2) ? (W_ih + gt * LSTM_IN + 8 * q)
                                           : (W_hh + gt * LSTM_H + 8 * (q - 2));
            else if (c == 1) src = W_hh + gt * LSTM_H + 16 + 8 * q;
            else if (q < 2)  src = W_hh + gt * LSTM_H + 48 + 8 * q;
            float4 a = make_float4(0.f, 0.f, 0.f, 0.f);
            float4 b = make_float4(0.f, 0.f, 0.f, 0.f);
            if (src) {
                a = *reinterpret_cast<const float4*>(src);
                b = *reinterpret_cast<const float4*>(src + 4);
            }
            cvt8(a, b, Ahi[tt][c], Alo[tt][c]);
            pin4(Ahi[tt][c]);
            pin4(Alo[tt][c]);
        }
        const int gb = wave * 64 + tt * 16 + 4 * q;    // gates for C regs r=0..3
        float4 bi = *reinterpret_cast<const float4*>(b_ih + gb);
        float4 bh = *reinterpret_cast<const float4*>(b_hh + gb);
        bias4[tt] = make_float4(bi.x + bh.x, bi.y + bh.y, bi.z + bh.z, bi.w + bh.w);
        pinf4(bias4[tt]);
    }

    // ---- init: h=0, pad=0, x(t=0) ----
    float cst = 0.0f;                                  // c[b][j] for tid<128
    if (tid < BT * XH) reinterpret_cast<short*>(xh)[tid] = 0;
    if (tid < BT * LSTM_IN) {
        int b = tid >> 4, i = tid & 15;
        float xv = x[(size_t)(bbase + b) * LSTM_T * LSTM_IN + i];
        xh[b][i] = (short)f2bf(xv);
    }
    __syncthreads();

    for (int t = 0; t < LSTM_T; ++t) {
        // prefetch next step's x (global latency hidden behind mfma+act)
        float xnext = 0.0f;
        if (tid < BT * LSTM_IN && t + 1 < LSTM_T) {
            int b = tid >> 4, i = tid & 15;
            xnext = x[(size_t)(bbase + b) * LSTM_T * LSTM_IN + (t + 1) * LSTM_IN + i];
        }

        // ---- Phase A: G = W_hi.xh + W_lo.xh + bias via MFMA ----
        floatx4 acc[4];
        #pragma unroll
        for (int tt = 0; tt < 4; ++tt) {
            acc[tt][0] = bias4[tt].x; acc[tt][1] = bias4[tt].y;
            acc[tt][2] = bias4[tt].z; acc[tt][3] = bias4[tt].w;
        }
        #pragma unroll
        for (int c = 0; c < 3; ++c) {
            short8 bfr = *reinterpret_cast<const short8*>(
                reinterpret_cast<const short*>(xh) + nb * XH + 32 * c + 8 * q);
            #pragma unroll
            for (int tt = 0; tt < 4; ++tt) {
                acc[tt] = __builtin_amdgcn_mfma_f32_16x16x32_bf16(
                    __builtin_bit_cast(short8, Ahi[tt][c]), bfr, acc[tt], 0, 0, 0);
                acc[tt] = __builtin_amdgcn_mfma_f32_16x16x32_bf16(
                    __builtin_bit_cast(short8, Alo[tt][c]), bfr, acc[tt], 0, 0, 0);
            }
        }

        // ---- Phase B: store preacts (C cols 0,1 = batches; rows 4q+r) ----
        if (m < BT) {
            #pragma unroll
            for (int tt = 0; tt < 4; ++tt) {
                float4 v = make_float4(acc[tt][0], acc[tt][1], acc[tt][2], acc[tt][3]);
                *reinterpret_cast<float4*>(&pre[m][wave * 64 + tt * 16 + 4 * q]) = v;
            }
        }
        __syncthreads();

        // ---- Phase C/D: activate + state update, (b,j) per thread ----
        if (tid < BT * LSTM_H) {
            int b = tid >> 6, j = tid & 63;
            float gi = sigm(pre[b][j]);
            float gf = sigm(pre[b][64 + j]);
            float gg = tanh_(pre[b][128 + j]);
            float go = sigm(pre[b][192 + j]);
            cst = fmaf(gf, cst, gi * gg);
            float h = go * tanh_(cst);
            xh[b][16 + j] = (short)f2bf(h);   // bf16 h for next step's B-frag
            pre[b][j] = h;                    // fp32 h (final step feeds FC)
        }
        if (tid < BT * LSTM_IN) {
            int b = tid >> 4, i = tid & 15;
            xh[b][i] = (short)f2bf(xnext);    // x for step t+1
        }
        __syncthreads();
    }

    // ---- epilogue: out[b][o] = sigmoid(h . W_fc[o] + b_fc[o]) ----
    if (tid < BT * LSTM_OUT) {
        int b = tid >> 3, o = tid & 7;
        float s = b_fc[o];
        #pragma unroll 8
        for (int j = 0; j < LSTM_H; ++j) s = fmaf(W_fc[o * LSTM_H + j], pre[b][j], s);
        out[(size_t)(bbase + b) * LSTM_OUT + o] = sigm(s);
    }
}

extern "C" void kernel_launch(void* const* d_in, const int* in_sizes, int n_in,
                              void* d_out, int out_size, void* d_ws, size_t ws_size,
                              hipStream_t stream) {
    const float* x    = (const float*)d_in[0];
    const float* W_ih = (const float*)d_in[1];
    const float* W_hh = (const float*)d_in[2];
    const float* b_ih = (const float*)d_in[3];
    const float* b_hh = (const float*)d_in[4];
    const float* W_fc = (const float*)d_in[5];
    const float* b_fc = (const float*)d_in[6];
    float* out = (float*)d_out;

    lstm_mfma_kernel<<<1024 / BT, 256, 0, stream>>>(
        x, W_ih, W_hh, b_ih, b_hh, W_fc, b_fc, out);
}